// Round 1
// 169.447 us; speedup vs baseline: 1.0429x; 1.0429x over previous
//
#include <hip/hip_runtime.h>
#include <hip/hip_fp16.h>

// GAT (2 heads x 64) + PReLU, N=50000, E=800000, feat 128.
// R11: finer binning buckets for machine coverage.
//  - NB 49 -> 196 (bucket = 256 dst nodes, b = d>>8): kD_fine now runs 196
//    blocks (196 CUs) instead of 49 (19% of chip). CCAP 160 -> 64 keeps a
//    9.4-sigma overflow margin (old config was 8.4 sigma) and makes the
//    kD pair index a pow2 shift (HALF=32) instead of a magic-div by 80.
//  - kB: lcnt now 196 counters -> 4x less wave-level same-address LDS-atomic
//    serialization. Everything else unchanged from R10.

#define N_NODES 50000
#define N_EDGES 800000
#define CAP     56        // max in-degree; deg ~ Poisson(16), P(>56) ~ 1e-9
#define BSH     8         // bucket shift: 256 nodes per bucket
#define NB      196       // ceil(N / 256) buckets
#define CHUNK   4096      // edges per kB block
#define NBLK    196       // ceil(E / CHUNK)
#define CCAP    64        // slots per (bucket,chunk) cell; mean 20.9, 9.4 sigma

// d_ws layout (bytes); total 36,237,120 (proven footprint)
#define OFF_A      0          // a_all: N*4 floats          =   800000
#define OFF_CNT    800000     // cnt:   N ints              =   200000
#define OFF_XS     1000256    // xs:    N*128 halves        = 12800000
#define OFF_BKT    13800256   // bkt:   N*CAP int2          = 22400000
#define OFF_SWZ    36200256   // swizzled B: 2304 * 16 B    =    36864
// d_out scratch (dead before k6 overwrites all 25.6 MB):
#define DOUT_COARSE 0         // NB*NBLK*CCAP*8 = 196*196*64*8 = 19,668,992
#define DOUT_CELL   19668992  // cellcnt = NB*NBLK*4 = 153,664 B
                              // total 19,822,656 < 25,600,000 (d_out)

typedef _Float16 f16x8 __attribute__((ext_vector_type(8)));
typedef float    f32x4 __attribute__((ext_vector_type(4)));
typedef unsigned long long u64;

// ---------------------------------------------------------------------------
// k0_prep: build B-fragment buffer for GEMM x @ [W_src | V].
// Entry (kb, nt, lane): 8 halves B[k = kb*32+(lane>>4)*8+j][n = nt*16+(lane&15)].
// nt 0..7 = W_src cols; nt 8 cols 0..3 = V (att-reduced W_src/W_dst).
__global__ __launch_bounds__(256) void k0_prep(
    const float* __restrict__ Wsrc, const float* __restrict__ Wdst,
    const float* __restrict__ att_s, const float* __restrict__ att_d,
    __half* __restrict__ swz)
{
    __shared__ float vS[128 * 4];
    const int nt = blockIdx.x;
    const int t = threadIdx.x;
    if (nt == 8) {
        if (t < 128) {
            const float* wsp = Wsrc + t * 128;
            const float* wdp = Wdst + t * 128;
            float a0 = 0.f, a1 = 0.f, a2 = 0.f, a3 = 0.f;
#pragma unroll 8
            for (int c = 0; c < 64; ++c) {
                a0 += wsp[c]      * att_s[c];
                a1 += wsp[64 + c] * att_s[64 + c];
                a2 += wdp[c]      * att_d[c];
                a3 += wdp[64 + c] * att_d[64 + c];
            }
            *(float4*)(vS + t * 4) = make_float4(a0, a1, a2, a3);
        }
        __syncthreads();
    }
    const int kb = t >> 6, L = t & 63;
    const int col = L & 15;
    const int krow = kb * 32 + ((L >> 4) & 3) * 8;
    f16x8 v;
    if (nt < 8) {
#pragma unroll
        for (int j = 0; j < 8; ++j)
            v[j] = (_Float16)Wsrc[(size_t)(krow + j) * 128 + nt * 16 + col];
    } else {
#pragma unroll
        for (int j = 0; j < 8; ++j)
            v[j] = (col < 4) ? (_Float16)vS[(krow + j) * 4 + col] : (_Float16)0.f;
    }
    *(f16x8*)(swz + ((size_t)(kb * 9 + nt) * 64 + L) * 8) = v;
}

// ---------------------------------------------------------------------------
// k1: MFMA GEMM x @ [W_src | V]. Block = 4 waves; wave: 16 rows x 144 cols, K=128.
// Epilogue: acc -> LDS (b16 writes) -> coalesced dwordx4 global stores.
__global__ __launch_bounds__(256) void k1_gemm(
    const float* __restrict__ x, const __half* __restrict__ swz,
    __half* __restrict__ xs, float* __restrict__ a_all)
{
    __shared__ __half tile[64 * 136];   // row stride 272B (16B-mult); 17.4 KB
    const int t = threadIdx.x;
    const int w = t >> 6, L = t & 63;
    const int m = L & 15, q = L >> 4;
    const int n_a = blockIdx.x * 64 + w * 16 + m;
    const int rrow = (n_a < N_NODES) ? n_a : (N_NODES - 1);
    const float* xrow = x + (size_t)rrow * 128;

    f32x4 acc[9];
#pragma unroll
    for (int nt = 0; nt < 9; ++nt) acc[nt] = (f32x4){0.f, 0.f, 0.f, 0.f};

#pragma unroll
    for (int kb = 0; kb < 4; ++kb) {
        const int k0 = kb * 32 + q * 8;
        float4 xa = *(const float4*)(xrow + k0);
        float4 xb = *(const float4*)(xrow + k0 + 4);
        f16x8 a;
        a[0] = (_Float16)xa.x; a[1] = (_Float16)xa.y;
        a[2] = (_Float16)xa.z; a[3] = (_Float16)xa.w;
        a[4] = (_Float16)xb.x; a[5] = (_Float16)xb.y;
        a[6] = (_Float16)xb.z; a[7] = (_Float16)xb.w;
        const f16x8* bbase = (const f16x8*)swz + (size_t)(kb * 9) * 64 + L;
#pragma unroll
        for (int nt = 0; nt < 9; ++nt) {
            f16x8 b = bbase[(size_t)nt * 64];
            acc[nt] = __builtin_amdgcn_mfma_f32_16x16x32_f16(a, b, acc[nt], 0, 0, 0);
        }
    }

    // xs epilogue: C/D layout col = lane&15, row = (lane>>4)*4 + reg
    const int rloc = w * 16 + q * 4;              // row-in-tile base for this lane
#pragma unroll
    for (int nt = 0; nt < 8; ++nt) {
#pragma unroll
        for (int r = 0; r < 4; ++r)
            tile[(rloc + r) * 136 + nt * 16 + m] = (__half)acc[nt][r];
    }
    __syncthreads();
    const int n0 = blockIdx.x * 64;
#pragma unroll
    for (int cc = 0; cc < 4; ++cc) {
        int task = cc * 256 + t;                  // 1024 tasks = 64 rows x 16 chunks
        int row = task >> 4, ch = (task & 15) * 8;
        int n = n0 + row;
        if (n < N_NODES) {
            ulonglong2 v = *(const ulonglong2*)(tile + row * 136 + ch);
            *(ulonglong2*)(xs + (size_t)n * 128 + ch) = v;
        }
    }

    // a_all from tile 8 (fp32, 4 cols)
    if (m < 4) {
#pragma unroll
        for (int r = 0; r < 4; ++r) {
            int n = n0 + rloc + r;
            if (n < N_NODES) a_all[(size_t)n * 4 + m] = acc[8][r];
        }
    }
}

// ---------------------------------------------------------------------------
// kB: per-chunk scatter into this chunk's private cells. LDS cursors only;
// zero global atomics; 2 edges/thread/iter via int2 loads.
__global__ __launch_bounds__(256) void kB_bin(
    const int* __restrict__ ei, const float* __restrict__ a_all,
    u64* __restrict__ coarse, int* __restrict__ cellcnt)
{
    __shared__ int lcnt[NB];
    const int t = threadIdx.x;
    if (t < NB) lcnt[t] = 0;
    __syncthreads();
    const int e0 = blockIdx.x * CHUNK;
#pragma unroll
    for (int u = 0; u < 8; ++u) {
        int e = e0 + u * 512 + t * 2;             // even; E even -> e+1 valid too
        if (e < N_EDGES) {
            int2 ss = *(const int2*)(ei + e);
            int2 dd = *(const int2*)(ei + N_EDGES + e);
            float2 as0 = *(const float2*)(a_all + (size_t)ss.x * 4);
            float2 ad0 = *(const float2*)(a_all + (size_t)dd.x * 4 + 2);
            float2 as1 = *(const float2*)(a_all + (size_t)ss.y * 4);
            float2 ad1 = *(const float2*)(a_all + (size_t)dd.y * 4 + 2);
            float e00 = as0.x + ad0.x, e01 = as0.y + ad0.y;
            float e10 = as1.x + ad1.x, e11 = as1.y + ad1.y;
            e00 = (e00 >= 0.f) ? e00 : 0.2f * e00;
            e01 = (e01 >= 0.f) ? e01 : 0.2f * e01;
            e10 = (e10 >= 0.f) ? e10 : 0.2f * e10;
            e11 = (e11 >= 0.f) ? e11 : 0.2f * e11;
            // no max-shift: |e| small -> exp safe in fp32, math identical
            __half2 hw0 = __floats2half2_rn(__expf(e00), __expf(e01));
            __half2 hw1 = __floats2half2_rn(__expf(e10), __expf(e11));
            unsigned lo0 = (unsigned)ss.x | ((unsigned)(dd.x & 255) << 16);
            unsigned lo1 = (unsigned)ss.y | ((unsigned)(dd.y & 255) << 16);
            u64 ent0 = (u64)lo0 | ((u64)*reinterpret_cast<unsigned*>(&hw0) << 32);
            u64 ent1 = (u64)lo1 | ((u64)*reinterpret_cast<unsigned*>(&hw1) << 32);
            int b0 = dd.x >> BSH, b1 = dd.y >> BSH;
            int p0 = atomicAdd(&lcnt[b0], 1);
            int p1 = atomicAdd(&lcnt[b1], 1);
            if (p0 < CCAP)
                coarse[((size_t)b0 * NBLK + blockIdx.x) * CCAP + p0] = ent0;
            if (p1 < CCAP)
                coarse[((size_t)b1 * NBLK + blockIdx.x) * CCAP + p1] = ent1;
        }
    }
    __syncthreads();
    if (t < NB) {
        int c = lcnt[t];
        cellcnt[t * NBLK + blockIdx.x] = (c < CCAP) ? c : CCAP;
    }
}

// ---------------------------------------------------------------------------
// kD: one 512-thread block per 256-node bucket; per-dst cursors in LDS;
// gap-skipping slot-PAIR (16B) reads; pow2 pair index (HALF=32);
// writes bkt rows + cnt, no global atomics.
__global__ __launch_bounds__(512) void kD_fine(
    const u64* __restrict__ coarse, const int* __restrict__ cellcnt,
    int* __restrict__ cnt, int2* __restrict__ bkt)
{
    __shared__ int cur[256];
    __shared__ int ccnt[NBLK];
    const int b = blockIdx.x, t = threadIdx.x;
    if (t < 256) cur[t] = 0;
    if (t < NBLK) ccnt[t] = cellcnt[b * NBLK + t];
    __syncthreads();
    const u64* src = coarse + (size_t)b * NBLK * CCAP;
    const int HALF = CCAP / 2;                       // 32 pairs per cell (pow2)
    for (int g2 = t; g2 < NBLK * HALF; g2 += 512) {
        int c = g2 >> 5, sp = (g2 & 31) * 2;
        int cc = ccnt[c];
        if (sp < cc) {
            ulonglong2 pr = *(const ulonglong2*)(src + (size_t)c * CCAP + sp);
            {
                unsigned lo = (unsigned)pr.x;
                int drel = (lo >> 16) & 255;
                int pos = atomicAdd(&cur[drel], 1);
                if (pos < CAP) {
                    int d = (b << BSH) + drel;
                    bkt[(size_t)d * CAP + pos] =
                        make_int2((int)(lo & 0xFFFF), (int)(unsigned)(pr.x >> 32));
                }
            }
            if (sp + 1 < cc) {
                unsigned lo = (unsigned)pr.y;
                int drel = (lo >> 16) & 255;
                int pos = atomicAdd(&cur[drel], 1);
                if (pos < CAP) {
                    int d = (b << BSH) + drel;
                    bkt[(size_t)d * CAP + pos] =
                        make_int2((int)(lo & 0xFFFF), (int)(unsigned)(pr.y >> 32));
                }
            }
        }
    }
    __syncthreads();
    if (t < 256) {
        int d = (b << BSH) + t;
        if (d < N_NODES) cnt[d] = cur[t];
    }
}

// ---------------------------------------------------------------------------
// k6: one wave per node; 8-wide edge unroll; predicated 8-wide tail.
template<bool GUARD>
__device__ __forceinline__ void step8(const int2* __restrict__ row, int k, int m,
                                      int sh, int j, const __half* __restrict__ xs,
                                      float& ax, float& ay, float& sw)
{
    int4 p0 = *(const int4*)(row + k);
    int4 p1 = *(const int4*)(row + k + 2);
    int4 p2 = *(const int4*)(row + k + 4);
    int4 p3 = *(const int4*)(row + k + 6);
    int s0 = p0.x, s1 = p0.z, s2 = p1.x, s3 = p1.z;
    int s4 = p2.x, s5 = p2.z, s6 = p3.x, s7 = p3.z;
    unsigned w0 = (unsigned)p0.y, w1 = (unsigned)p0.w;
    unsigned w2 = (unsigned)p1.y, w3 = (unsigned)p1.w;
    unsigned w4 = (unsigned)p2.y, w5 = (unsigned)p2.w;
    unsigned w6 = (unsigned)p3.y, w7 = (unsigned)p3.w;
    if (GUARD) {
        if (k + 0 >= m) { s0 = 0; w0 = 0; }
        if (k + 1 >= m) { s1 = 0; w1 = 0; }
        if (k + 2 >= m) { s2 = 0; w2 = 0; }
        if (k + 3 >= m) { s3 = 0; w3 = 0; }
        if (k + 4 >= m) { s4 = 0; w4 = 0; }
        if (k + 5 >= m) { s5 = 0; w5 = 0; }
        if (k + 6 >= m) { s6 = 0; w6 = 0; }
        if (k + 7 >= m) { s7 = 0; w7 = 0; }
    }
    __half2 h0 = *(const __half2*)(xs + (size_t)s0 * 128 + j);
    __half2 h1 = *(const __half2*)(xs + (size_t)s1 * 128 + j);
    __half2 h2 = *(const __half2*)(xs + (size_t)s2 * 128 + j);
    __half2 h3 = *(const __half2*)(xs + (size_t)s3 * 128 + j);
    __half2 h4 = *(const __half2*)(xs + (size_t)s4 * 128 + j);
    __half2 h5 = *(const __half2*)(xs + (size_t)s5 * 128 + j);
    __half2 h6 = *(const __half2*)(xs + (size_t)s6 * 128 + j);
    __half2 h7 = *(const __half2*)(xs + (size_t)s7 * 128 + j);
    float a0 = __half2float(__ushort_as_half((unsigned short)(w0 >> sh)));
    float a1 = __half2float(__ushort_as_half((unsigned short)(w1 >> sh)));
    float a2 = __half2float(__ushort_as_half((unsigned short)(w2 >> sh)));
    float a3 = __half2float(__ushort_as_half((unsigned short)(w3 >> sh)));
    float a4 = __half2float(__ushort_as_half((unsigned short)(w4 >> sh)));
    float a5 = __half2float(__ushort_as_half((unsigned short)(w5 >> sh)));
    float a6 = __half2float(__ushort_as_half((unsigned short)(w6 >> sh)));
    float a7 = __half2float(__ushort_as_half((unsigned short)(w7 >> sh)));
    ax += __half2float(h0.x) * a0; ay += __half2float(h0.y) * a0;
    ax += __half2float(h1.x) * a1; ay += __half2float(h1.y) * a1;
    ax += __half2float(h2.x) * a2; ay += __half2float(h2.y) * a2;
    ax += __half2float(h3.x) * a3; ay += __half2float(h3.y) * a3;
    ax += __half2float(h4.x) * a4; ay += __half2float(h4.y) * a4;
    ax += __half2float(h5.x) * a5; ay += __half2float(h5.y) * a5;
    ax += __half2float(h6.x) * a6; ay += __half2float(h6.y) * a6;
    ax += __half2float(h7.x) * a7; ay += __half2float(h7.y) * a7;
    sw += ((a0 + a1) + (a2 + a3)) + ((a4 + a5) + (a6 + a7));
}

__global__ __launch_bounds__(256) void k6_agg(
    const int2* __restrict__ bkt, const int* __restrict__ cnt,
    const __half* __restrict__ xs, const float* __restrict__ bias,
    const float* __restrict__ prelu_w, float* __restrict__ out)
{
    const int n = blockIdx.x * 4 + (threadIdx.x >> 6);
    const int lane = threadIdx.x & 63;
    const int j = lane * 2;
    const int sh = (lane >> 5) * 16;
    int m = cnt[n]; if (m > CAP) m = CAP;
    const int2* row = bkt + (size_t)n * CAP;
    float ax = 0.f, ay = 0.f, sw = 0.f;
    int k = 0;
    for (; k + 8 <= m; k += 8)
        step8<false>(row, k, m, sh, j, xs, ax, ay, sw);
    if (k < m)
        step8<true>(row, k, m, sh, j, xs, ax, ay, sw);

    float inv = 1.f / (sw + 1e-16f);
    float o0 = ax * inv + bias[j];
    float o1 = ay * inv + bias[j + 1];
    float2 r;
    r.x = (o0 >= 0.f) ? o0 : prelu_w[j] * o0;
    r.y = (o1 >= 0.f) ? o1 : prelu_w[j + 1] * o1;
    *(float2*)(out + (size_t)n * 128 + j) = r;
}

extern "C" void kernel_launch(void* const* d_in, const int* in_sizes, int n_in,
                              void* d_out, int out_size, void* d_ws, size_t ws_size,
                              hipStream_t stream) {
    const float* x      = (const float*)d_in[0];
    const float* Wsrc   = (const float*)d_in[1];
    const float* Wdst   = (const float*)d_in[2];
    const float* att_s  = (const float*)d_in[3];
    const float* att_d  = (const float*)d_in[4];
    const float* bias   = (const float*)d_in[5];
    const float* prelu  = (const float*)d_in[6];
    const int*   ei     = (const int*)d_in[7];
    float* out = (float*)d_out;

    char* ws = (char*)d_ws;
    float*  a_all  = (float*)(ws + OFF_A);
    int*    cnt    = (int*)(ws + OFF_CNT);
    __half* xs     = (__half*)(ws + OFF_XS);
    int2*   bkt    = (int2*)(ws + OFF_BKT);
    __half* swz    = (__half*)(ws + OFF_SWZ);

    char* outb = (char*)d_out;               // scratch; k6 overwrites all of it
    u64* coarse  = (u64*)(outb + DOUT_COARSE);
    int* cellcnt = (int*)(outb + DOUT_CELL);

    k0_prep<<<9, 256, 0, stream>>>(Wsrc, Wdst, att_s, att_d, swz);
    k1_gemm<<<(N_NODES + 63) / 64, 256, 0, stream>>>(x, swz, xs, a_all);
    kB_bin<<<NBLK, 256, 0, stream>>>(ei, a_all, coarse, cellcnt);
    kD_fine<<<NB, 512, 0, stream>>>(coarse, cellcnt, cnt, bkt);
    k6_agg<<<N_NODES / 4, 256, 0, stream>>>(bkt, cnt, xs, bias, prelu, out);
}

// Round 2
// 167.175 us; speedup vs baseline: 1.0571x; 1.0136x over previous
//
#include <hip/hip_runtime.h>
#include <hip/hip_fp16.h>

// GAT (2 heads x 64) + PReLU, N=50000, E=800000, feat 128.
// R12: fuse kD_fine + k6_agg into k5_binagg (per-bucket bin-to-LDS + aggregate).
//  - Eliminates the bkt (6.4 MB + RFO) / cnt global round-trip and one launch.
//  - Two blocks per 256-node bucket (each owns 128 dst via drel bit 7):
//    392 blocks x 512 thr, 58.6 KB LDS -> 2 blocks/CU, full-chip coverage.
//  - coarse/cellcnt moved to d_ws (freed bkt/cnt regions): the fused kernel
//    writes d_out while sibling blocks still read coarse, so coarse can no
//    longer alias d_out. kB geometry identical to R11 (proven).

#define N_NODES 50000
#define N_EDGES 800000
#define CAP     56        // max in-degree; deg ~ Poisson(16), P(>56) ~ 1e-9
#define BSH     8         // bucket shift: 256 nodes per bucket
#define NB      196       // ceil(N / 256) buckets
#define CHUNK   4096      // edges per kB block
#define NBLK    196       // ceil(E / CHUNK)
#define CCAP    64        // slots per (bucket,chunk) cell; mean 20.9, 9.4 sigma

// d_ws layout (bytes); total 36,237,120 (unchanged footprint)
#define OFF_A      0          // a_all:   N*4 floats            =    800000
#define OFF_CELL   800000     // cellcnt: NB*NBLK ints          =    153664 (<200256)
#define OFF_XS     1000256    // xs:      N*128 halves          =  12800000
#define OFF_COARSE 13800256   // coarse:  NB*NBLK*CCAP u64      =  19668992 (ends 33,469,248)
#define OFF_SWZ    36200256   // swizzled B: 2304 * 16 B        =     36864

typedef _Float16 f16x8 __attribute__((ext_vector_type(8)));
typedef float    f32x4 __attribute__((ext_vector_type(4)));
typedef unsigned long long u64;

// ---------------------------------------------------------------------------
// k0_prep: build B-fragment buffer for GEMM x @ [W_src | V].
// Entry (kb, nt, lane): 8 halves B[k = kb*32+(lane>>4)*8+j][n = nt*16+(lane&15)].
// nt 0..7 = W_src cols; nt 8 cols 0..3 = V (att-reduced W_src/W_dst).
__global__ __launch_bounds__(256) void k0_prep(
    const float* __restrict__ Wsrc, const float* __restrict__ Wdst,
    const float* __restrict__ att_s, const float* __restrict__ att_d,
    __half* __restrict__ swz)
{
    __shared__ float vS[128 * 4];
    const int nt = blockIdx.x;
    const int t = threadIdx.x;
    if (nt == 8) {
        if (t < 128) {
            const float* wsp = Wsrc + t * 128;
            const float* wdp = Wdst + t * 128;
            float a0 = 0.f, a1 = 0.f, a2 = 0.f, a3 = 0.f;
#pragma unroll 8
            for (int c = 0; c < 64; ++c) {
                a0 += wsp[c]      * att_s[c];
                a1 += wsp[64 + c] * att_s[64 + c];
                a2 += wdp[c]      * att_d[c];
                a3 += wdp[64 + c] * att_d[64 + c];
            }
            *(float4*)(vS + t * 4) = make_float4(a0, a1, a2, a3);
        }
        __syncthreads();
    }
    const int kb = t >> 6, L = t & 63;
    const int col = L & 15;
    const int krow = kb * 32 + ((L >> 4) & 3) * 8;
    f16x8 v;
    if (nt < 8) {
#pragma unroll
        for (int j = 0; j < 8; ++j)
            v[j] = (_Float16)Wsrc[(size_t)(krow + j) * 128 + nt * 16 + col];
    } else {
#pragma unroll
        for (int j = 0; j < 8; ++j)
            v[j] = (col < 4) ? (_Float16)vS[(krow + j) * 4 + col] : (_Float16)0.f;
    }
    *(f16x8*)(swz + ((size_t)(kb * 9 + nt) * 64 + L) * 8) = v;
}

// ---------------------------------------------------------------------------
// k1: MFMA GEMM x @ [W_src | V]. Block = 4 waves; wave: 16 rows x 144 cols, K=128.
// Epilogue: acc -> LDS (b16 writes) -> coalesced dwordx4 global stores.
__global__ __launch_bounds__(256) void k1_gemm(
    const float* __restrict__ x, const __half* __restrict__ swz,
    __half* __restrict__ xs, float* __restrict__ a_all)
{
    __shared__ __half tile[64 * 136];   // row stride 272B (16B-mult); 17.4 KB
    const int t = threadIdx.x;
    const int w = t >> 6, L = t & 63;
    const int m = L & 15, q = L >> 4;
    const int n_a = blockIdx.x * 64 + w * 16 + m;
    const int rrow = (n_a < N_NODES) ? n_a : (N_NODES - 1);
    const float* xrow = x + (size_t)rrow * 128;

    f32x4 acc[9];
#pragma unroll
    for (int nt = 0; nt < 9; ++nt) acc[nt] = (f32x4){0.f, 0.f, 0.f, 0.f};

#pragma unroll
    for (int kb = 0; kb < 4; ++kb) {
        const int k0 = kb * 32 + q * 8;
        float4 xa = *(const float4*)(xrow + k0);
        float4 xb = *(const float4*)(xrow + k0 + 4);
        f16x8 a;
        a[0] = (_Float16)xa.x; a[1] = (_Float16)xa.y;
        a[2] = (_Float16)xa.z; a[3] = (_Float16)xa.w;
        a[4] = (_Float16)xb.x; a[5] = (_Float16)xb.y;
        a[6] = (_Float16)xb.z; a[7] = (_Float16)xb.w;
        const f16x8* bbase = (const f16x8*)swz + (size_t)(kb * 9) * 64 + L;
#pragma unroll
        for (int nt = 0; nt < 9; ++nt) {
            f16x8 b = bbase[(size_t)nt * 64];
            acc[nt] = __builtin_amdgcn_mfma_f32_16x16x32_f16(a, b, acc[nt], 0, 0, 0);
        }
    }

    // xs epilogue: C/D layout col = lane&15, row = (lane>>4)*4 + reg
    const int rloc = w * 16 + q * 4;              // row-in-tile base for this lane
#pragma unroll
    for (int nt = 0; nt < 8; ++nt) {
#pragma unroll
        for (int r = 0; r < 4; ++r)
            tile[(rloc + r) * 136 + nt * 16 + m] = (__half)acc[nt][r];
    }
    __syncthreads();
    const int n0 = blockIdx.x * 64;
#pragma unroll
    for (int cc = 0; cc < 4; ++cc) {
        int task = cc * 256 + t;                  // 1024 tasks = 64 rows x 16 chunks
        int row = task >> 4, ch = (task & 15) * 8;
        int n = n0 + row;
        if (n < N_NODES) {
            ulonglong2 v = *(const ulonglong2*)(tile + row * 136 + ch);
            *(ulonglong2*)(xs + (size_t)n * 128 + ch) = v;
        }
    }

    // a_all from tile 8 (fp32, 4 cols)
    if (m < 4) {
#pragma unroll
        for (int r = 0; r < 4; ++r) {
            int n = n0 + rloc + r;
            if (n < N_NODES) a_all[(size_t)n * 4 + m] = acc[8][r];
        }
    }
}

// ---------------------------------------------------------------------------
// kB: per-chunk scatter into this chunk's private cells. LDS cursors only;
// zero global atomics; 2 edges/thread/iter via int2 loads. (Identical to R11.)
__global__ __launch_bounds__(256) void kB_bin(
    const int* __restrict__ ei, const float* __restrict__ a_all,
    u64* __restrict__ coarse, int* __restrict__ cellcnt)
{
    __shared__ int lcnt[NB];
    const int t = threadIdx.x;
    if (t < NB) lcnt[t] = 0;
    __syncthreads();
    const int e0 = blockIdx.x * CHUNK;
#pragma unroll
    for (int u = 0; u < 8; ++u) {
        int e = e0 + u * 512 + t * 2;             // even; E even -> e+1 valid too
        if (e < N_EDGES) {
            int2 ss = *(const int2*)(ei + e);
            int2 dd = *(const int2*)(ei + N_EDGES + e);
            float2 as0 = *(const float2*)(a_all + (size_t)ss.x * 4);
            float2 ad0 = *(const float2*)(a_all + (size_t)dd.x * 4 + 2);
            float2 as1 = *(const float2*)(a_all + (size_t)ss.y * 4);
            float2 ad1 = *(const float2*)(a_all + (size_t)dd.y * 4 + 2);
            float e00 = as0.x + ad0.x, e01 = as0.y + ad0.y;
            float e10 = as1.x + ad1.x, e11 = as1.y + ad1.y;
            e00 = (e00 >= 0.f) ? e00 : 0.2f * e00;
            e01 = (e01 >= 0.f) ? e01 : 0.2f * e01;
            e10 = (e10 >= 0.f) ? e10 : 0.2f * e10;
            e11 = (e11 >= 0.f) ? e11 : 0.2f * e11;
            // no max-shift: |e| small -> exp safe in fp32, math identical
            __half2 hw0 = __floats2half2_rn(__expf(e00), __expf(e01));
            __half2 hw1 = __floats2half2_rn(__expf(e10), __expf(e11));
            unsigned lo0 = (unsigned)ss.x | ((unsigned)(dd.x & 255) << 16);
            unsigned lo1 = (unsigned)ss.y | ((unsigned)(dd.y & 255) << 16);
            u64 ent0 = (u64)lo0 | ((u64)*reinterpret_cast<unsigned*>(&hw0) << 32);
            u64 ent1 = (u64)lo1 | ((u64)*reinterpret_cast<unsigned*>(&hw1) << 32);
            int b0 = dd.x >> BSH, b1 = dd.y >> BSH;
            int p0 = atomicAdd(&lcnt[b0], 1);
            int p1 = atomicAdd(&lcnt[b1], 1);
            if (p0 < CCAP)
                coarse[((size_t)b0 * NBLK + blockIdx.x) * CCAP + p0] = ent0;
            if (p1 < CCAP)
                coarse[((size_t)b1 * NBLK + blockIdx.x) * CCAP + p1] = ent1;
        }
    }
    __syncthreads();
    if (t < NB) {
        int c = lcnt[t];
        cellcnt[t * NBLK + blockIdx.x] = (c < CCAP) ? c : CCAP;
    }
}

// ---------------------------------------------------------------------------
// step8: 8-edge unrolled weighted gather-accumulate. row points into LDS.
template<bool GUARD>
__device__ __forceinline__ void step8(const int2* __restrict__ row, int k, int m,
                                      int sh, int j, const __half* __restrict__ xs,
                                      float& ax, float& ay, float& sw)
{
    int4 p0 = *(const int4*)(row + k);
    int4 p1 = *(const int4*)(row + k + 2);
    int4 p2 = *(const int4*)(row + k + 4);
    int4 p3 = *(const int4*)(row + k + 6);
    int s0 = p0.x, s1 = p0.z, s2 = p1.x, s3 = p1.z;
    int s4 = p2.x, s5 = p2.z, s6 = p3.x, s7 = p3.z;
    unsigned w0 = (unsigned)p0.y, w1 = (unsigned)p0.w;
    unsigned w2 = (unsigned)p1.y, w3 = (unsigned)p1.w;
    unsigned w4 = (unsigned)p2.y, w5 = (unsigned)p2.w;
    unsigned w6 = (unsigned)p3.y, w7 = (unsigned)p3.w;
    if (GUARD) {
        if (k + 0 >= m) { s0 = 0; w0 = 0; }
        if (k + 1 >= m) { s1 = 0; w1 = 0; }
        if (k + 2 >= m) { s2 = 0; w2 = 0; }
        if (k + 3 >= m) { s3 = 0; w3 = 0; }
        if (k + 4 >= m) { s4 = 0; w4 = 0; }
        if (k + 5 >= m) { s5 = 0; w5 = 0; }
        if (k + 6 >= m) { s6 = 0; w6 = 0; }
        if (k + 7 >= m) { s7 = 0; w7 = 0; }
    }
    __half2 h0 = *(const __half2*)(xs + (size_t)s0 * 128 + j);
    __half2 h1 = *(const __half2*)(xs + (size_t)s1 * 128 + j);
    __half2 h2 = *(const __half2*)(xs + (size_t)s2 * 128 + j);
    __half2 h3 = *(const __half2*)(xs + (size_t)s3 * 128 + j);
    __half2 h4 = *(const __half2*)(xs + (size_t)s4 * 128 + j);
    __half2 h5 = *(const __half2*)(xs + (size_t)s5 * 128 + j);
    __half2 h6 = *(const __half2*)(xs + (size_t)s6 * 128 + j);
    __half2 h7 = *(const __half2*)(xs + (size_t)s7 * 128 + j);
    float a0 = __half2float(__ushort_as_half((unsigned short)(w0 >> sh)));
    float a1 = __half2float(__ushort_as_half((unsigned short)(w1 >> sh)));
    float a2 = __half2float(__ushort_as_half((unsigned short)(w2 >> sh)));
    float a3 = __half2float(__ushort_as_half((unsigned short)(w3 >> sh)));
    float a4 = __half2float(__ushort_as_half((unsigned short)(w4 >> sh)));
    float a5 = __half2float(__ushort_as_half((unsigned short)(w5 >> sh)));
    float a6 = __half2float(__ushort_as_half((unsigned short)(w6 >> sh)));
    float a7 = __half2float(__ushort_as_half((unsigned short)(w7 >> sh)));
    ax += __half2float(h0.x) * a0; ay += __half2float(h0.y) * a0;
    ax += __half2float(h1.x) * a1; ay += __half2float(h1.y) * a1;
    ax += __half2float(h2.x) * a2; ay += __half2float(h2.y) * a2;
    ax += __half2float(h3.x) * a3; ay += __half2float(h3.y) * a3;
    ax += __half2float(h4.x) * a4; ay += __half2float(h4.y) * a4;
    ax += __half2float(h5.x) * a5; ay += __half2float(h5.y) * a5;
    ax += __half2float(h6.x) * a6; ay += __half2float(h6.y) * a6;
    ax += __half2float(h7.x) * a7; ay += __half2float(h7.y) * a7;
    sw += ((a0 + a1) + (a2 + a3)) + ((a4 + a5) + (a6 + a7));
}

// ---------------------------------------------------------------------------
// k5_binagg: fused kD+k6. Two blocks per 256-node bucket; block owns 128 dst
// nodes (drel bit 7 == blockIdx&1). Phase A: gap-skipping slot-pair reads of
// this bucket's coarse cells, filter-own-half, bin into LDS rows (LDS-atomic
// cursors). Phase B: per-wave aggregation straight from LDS rows + xs gather.
__global__ __launch_bounds__(512, 4) void k5_binagg(
    const u64* __restrict__ coarse, const int* __restrict__ cellcnt,
    const __half* __restrict__ xs, const float* __restrict__ bias,
    const float* __restrict__ prelu_w, float* __restrict__ out)
{
    __shared__ __align__(16) int2 bl[128 * CAP];   // 57,344 B
    __shared__ int cur[128];
    __shared__ int ccnt[NBLK];
    const int t = threadIdx.x;
    const int b = blockIdx.x >> 1;
    const int hi = (blockIdx.x & 1) << 7;          // which 128-node half we own
    if (t < 128) cur[t] = 0;
    if (t < NBLK) ccnt[t] = cellcnt[b * NBLK + t];
    __syncthreads();

    const u64* src = coarse + (size_t)b * NBLK * CCAP;
    const int HALF = CCAP / 2;                     // 32 pairs per cell (pow2)
    for (int g2 = t; g2 < NBLK * HALF; g2 += 512) {
        int c = g2 >> 5, sp = (g2 & 31) * 2;
        int cc = ccnt[c];
        if (sp < cc) {
            ulonglong2 pr = *(const ulonglong2*)(src + (size_t)c * CCAP + sp);
            {
                unsigned lo = (unsigned)pr.x;
                int drel = (lo >> 16) & 255;
                if ((drel & 128) == hi) {
                    int rel = drel & 127;
                    int pos = atomicAdd(&cur[rel], 1);
                    if (pos < CAP)
                        bl[rel * CAP + pos] =
                            make_int2((int)(lo & 0xFFFF), (int)(unsigned)(pr.x >> 32));
                }
            }
            if (sp + 1 < cc) {
                unsigned lo = (unsigned)pr.y;
                int drel = (lo >> 16) & 255;
                if ((drel & 128) == hi) {
                    int rel = drel & 127;
                    int pos = atomicAdd(&cur[rel], 1);
                    if (pos < CAP)
                        bl[rel * CAP + pos] =
                            make_int2((int)(lo & 0xFFFF), (int)(unsigned)(pr.y >> 32));
                }
            }
        }
    }
    __syncthreads();

    const int w = t >> 6, lane = t & 63;
    const int j = lane * 2;
    const int sh = (lane >> 5) * 16;
    const float bj0 = bias[j], bj1 = bias[j + 1];
    const float pj0 = prelu_w[j], pj1 = prelu_w[j + 1];
#pragma unroll 1
    for (int i = 0; i < 16; ++i) {
        const int rel = w * 16 + i;
        const int d = (b << BSH) + hi + rel;
        if (d >= N_NODES) break;                   // only trailing nodes invalid
        int m = cur[rel]; if (m > CAP) m = CAP;
        const int2* row = bl + rel * CAP;          // LDS; broadcast reads
        float ax = 0.f, ay = 0.f, sw = 0.f;
        int k = 0;
        for (; k + 8 <= m; k += 8)
            step8<false>(row, k, m, sh, j, xs, ax, ay, sw);
        if (k < m)
            step8<true>(row, k, m, sh, j, xs, ax, ay, sw);
        float inv = 1.f / (sw + 1e-16f);
        float o0 = ax * inv + bj0;
        float o1 = ay * inv + bj1;
        float2 r;
        r.x = (o0 >= 0.f) ? o0 : pj0 * o0;
        r.y = (o1 >= 0.f) ? o1 : pj1 * o1;
        *(float2*)(out + (size_t)d * 128 + j) = r;
    }
}

extern "C" void kernel_launch(void* const* d_in, const int* in_sizes, int n_in,
                              void* d_out, int out_size, void* d_ws, size_t ws_size,
                              hipStream_t stream) {
    const float* x      = (const float*)d_in[0];
    const float* Wsrc   = (const float*)d_in[1];
    const float* Wdst   = (const float*)d_in[2];
    const float* att_s  = (const float*)d_in[3];
    const float* att_d  = (const float*)d_in[4];
    const float* bias   = (const float*)d_in[5];
    const float* prelu  = (const float*)d_in[6];
    const int*   ei     = (const int*)d_in[7];
    float* out = (float*)d_out;

    char* ws = (char*)d_ws;
    float*  a_all   = (float*)(ws + OFF_A);
    int*    cellcnt = (int*)(ws + OFF_CELL);
    __half* xs      = (__half*)(ws + OFF_XS);
    u64*    coarse  = (u64*)(ws + OFF_COARSE);
    __half* swz     = (__half*)(ws + OFF_SWZ);

    k0_prep<<<9, 256, 0, stream>>>(Wsrc, Wdst, att_s, att_d, swz);
    k1_gemm<<<(N_NODES + 63) / 64, 256, 0, stream>>>(x, swz, xs, a_all);
    kB_bin<<<NBLK, 256, 0, stream>>>(ei, a_all, coarse, cellcnt);
    k5_binagg<<<NB * 2, 512, 0, stream>>>(coarse, cellcnt, xs, bias, prelu, out);
}